// Round 19
// baseline (326.895 us; speedup 1.0000x reference)
//
#include <hip/hip_runtime.h>
#include <cfloat>
#include <cmath>
#include <cstdint>

#define N_TOK 65536
#define N_E   2048
#define E_DIM 256
#define BETA  0.25

#define MGN 8e-4f     // capture margin; worst-case requirement ~6e-4
#define CMAX 16

// ws layout (bytes)
#define WS_LOSSPART 0          // double[512]     -> 4096
#define WS_A        16384      // float[65536]    -> 278528
#define WS_B        278528     // float[2048]     -> 286720
#define WS_IDXF     286720     // int[65536]      -> 548864
#define WS_COUNTS   548864     // int[2048]       -> 557056
#define WS_CCNT     2654208    // int[65536]      -> 2916352
#define WS_CAND     2916352    // ushort[65536*16]-> 5013504

typedef __attribute__((ext_vector_type(8))) _Float16 half8;
typedef __attribute__((ext_vector_type(4))) float f32x4;

__device__ __forceinline__ ushort f2h(float f) {
  union { _Float16 h; ushort u; } c;
  c.h = (_Float16)f;   // RNE
  return c.u;
}

__device__ __forceinline__ void gload_lds16(const void* g, void* l) {
  __builtin_amdgcn_global_load_lds(
      (const __attribute__((address_space(1))) unsigned int*)(g),
      (__attribute__((address_space(3))) unsigned int*)(l), 16, 0, 0);
}

__device__ __forceinline__ float4 f4add(float4 x, float4 y) {
  float4 r;
  r.x = __fadd_rn(x.x, y.x); r.y = __fadd_rn(x.y, y.y);
  r.z = __fadd_rn(x.z, y.z); r.w = __fadd_rn(x.w, y.w);
  return r;
}

__device__ __forceinline__ float4 f4shfl_xor(float4 x, int m) {
  float4 r;
  r.x = __shfl_xor(x.x, m, 64);
  r.y = __shfl_xor(x.y, m, 64);
  r.z = __shfl_xor(x.z, m, 64);
  r.w = __shfl_xor(x.w, m, 64);
  return r;
}

// exact sequential fused-FMA chain (verified bit-exact vs numpy sgemm, R3)
__device__ __forceinline__ float chain_m(const float* __restrict__ zp,
                                         const float* __restrict__ ep) {
  float acc = 0.f;
  for (int k = 0; k < E_DIM; k += 4) {
    const float4 zz = *(const float4*)(zp + k);
    const float4 ee = *(const float4*)(ep + k);
    acc = __fmaf_rn(zz.x, ee.x, acc);
    acc = __fmaf_rn(zz.y, ee.y, acc);
    acc = __fmaf_rn(zz.z, ee.z, acc);
    acc = __fmaf_rn(zz.w, ee.w, acc);
  }
  return acc;
}

// ---------------------------------------------------------------------------
// k_prep v2 (R18, verified): wave-cooperative coalesced convert + exact
// numpy pairwise tree via shuffles (bit-identical to R3's scalar version).
// ---------------------------------------------------------------------------
__global__ __launch_bounds__(256) void k_prep(
    const float* __restrict__ z, const float* __restrict__ E,
    ushort* __restrict__ zf, ushort* __restrict__ ef,
    float* __restrict__ a, float* __restrict__ b, int* __restrict__ counts) {
  if (blockIdx.x == 0) {
    for (int i = threadIdx.x; i < N_E; i += 256) counts[i] = 0;
  }
  const int l = threadIdx.x & 63;
  const int gw = blockIdx.x * 4 + (threadIdx.x >> 6);   // global wave id
  const int NROW = N_TOK + N_E;                          // 67584 rows

  for (int row = gw; row < NROW; row += 2048 * 4) {
    const bool isZ = row < N_TOK;
    const int lr = isZ ? row : row - N_TOK;
    const float* src = (isZ ? z + (size_t)lr * E_DIM : E + (size_t)lr * E_DIM);
    ushort* dst = (isZ ? zf + (size_t)lr * E_DIM : ef + (size_t)lr * E_DIM);
    const float scale = isZ ? 1.0f : 2048.0f;

    const float4 v = *(const float4*)(src + l * 4);
    ushort4 o;
    o.x = f2h(v.x * scale); o.y = f2h(v.y * scale);
    o.z = f2h(v.z * scale); o.w = f2h(v.w * scale);
    *(ushort4*)(dst + l * 4) = o;

    float4 q;
    q.x = __fmul_rn(v.x, v.x); q.y = __fmul_rn(v.y, v.y);
    q.z = __fmul_rn(v.z, v.z); q.w = __fmul_rn(v.w, v.w);

    float4 s1 = f4add(q, f4shfl_xor(q, 4));
    float4 s2 = f4add(s1, f4shfl_xor(s1, 8));
    float4 s3 = f4add(s2, f4shfl_xor(s2, 16));
    float4 u4 = f4add(s3, f4shfl_xor(s3, 2));
    float4 v4 = f4add(u4, f4shfl_xor(u4, 1));
    const float w0 = __fadd_rn(v4.x, v4.z);
    const float w1 = __fadd_rn(v4.y, v4.w);
    const float blk = __fadd_rn(w0, w1);
    const float other = __shfl_xor(blk, 32, 64);
    const float s = __fadd_rn(blk, other);

    if (l == 0) {
      if (isZ) a[lr] = s; else b[lr] = s;
    }
  }
}

// ---------------------------------------------------------------------------
// MFMA filter v10b = R16 (measured 124.7us) + WINDOWED butterfly: shuffle-
// min reduce at ct==0 and odd ct only (17/32 tiles, halves shuffle DS ops).
// On skip tiles the push gate = min(runmin, lane-pending incl. this tile)
// + MGN — a looser (sound) gate; final refilter still uses the exact full
// min (last butterfly at ct=31). Candidate structure unchanged from R16.
// ---------------------------------------------------------------------------
__global__ __launch_bounds__(512) void k_mfma(
    const ushort* __restrict__ zf, const ushort* __restrict__ ef,
    const float* __restrict__ b, int* __restrict__ gcnt,
    ushort* __restrict__ gcand) {
  extern __shared__ char sm[];
  // [0, 65536): B double buffer (2 x 32 KB, fragment-linear)
  int*    s_cnt  = (int*)(sm + 65536);    // 128 ints
  ushort* s_idx  = (ushort*)(sm + 66048); // 128*16
  float*  s_val  = (float*)(sm + 70144);  // 128*16
  float*  s_rmin = (float*)(sm + 78336);  // 128 floats (end 78848)

  const int tid = threadIdx.x;
  const int wv  = tid >> 6;      // 0..7
  const int l   = tid & 63;
  const int c16 = l & 15;
  const int kb  = l >> 4;
  const int tokBase = blockIdx.x * 128 + wv * 16;

  if (tid < 128) s_cnt[tid] = 0;

  // A fragments: 16 tokens x K=256 (8 chunks of 32), resident in VGPRs
  half8 Az[8];
  {
    const ushort* za = zf + (size_t)(tokBase + c16) * E_DIM + kb * 8;
#pragma unroll
    for (int kk = 0; kk < 8; ++kk) Az[kk] = *(const half8*)(za + kk * 32);
  }

  // prologue: stage panel 0 into buffer 0 (fragment-permuted source)
#pragma unroll
  for (int i = 0; i < 4; ++i) {
    const int g = i * 512 + tid;                 // 16B granule id, 0..2047
    const int cg = g >> 9, kk = (g >> 6) & 7;
    const int cs = g & 15, ks = (g >> 4) & 3;
    gload_lds16(ef + (size_t)(cg * 16 + cs) * E_DIM + kk * 32 + ks * 8,
                sm + g * 16);
  }
  __syncthreads();

  float runmin[4] = {FLT_MAX, FLT_MAX, FLT_MAX, FLT_MAX};
  float pmin[4]   = {FLT_MAX, FLT_MAX, FLT_MAX, FLT_MAX};

  for (int ct = 0; ct < 32; ++ct) {
    const int cur = ct & 1;
    if (ct + 1 < 32) {
      const ushort* panel = ef + (size_t)(ct + 1) * (64 * E_DIM);
      char* dst = sm + (cur ^ 1) * 32768;
#pragma unroll
      for (int i = 0; i < 4; ++i) {
        const int g = i * 512 + tid;
        const int cg = g >> 9, kk = (g >> 6) & 7;
        const int cs = g & 15, ks = (g >> 4) & 3;
        gload_lds16(panel + (size_t)(cg * 16 + cs) * E_DIM + kk * 32 + ks * 8,
                    dst + g * 16);
      }
    }
    float bc[4];
#pragma unroll
    for (int cg = 0; cg < 4; ++cg) bc[cg] = b[ct * 64 + cg * 16 + c16];

    f32x4 acc[4];
#pragma unroll
    for (int cg = 0; cg < 4; ++cg) acc[cg] = (f32x4){0.f, 0.f, 0.f, 0.f};

    const char* lb = sm + cur * 32768;
#pragma unroll
    for (int kk = 0; kk < 8; ++kk) {
      half8 Bf[4];
#pragma unroll
      for (int cg = 0; cg < 4; ++cg)
        Bf[cg] = *(const half8*)(lb + ((((cg << 3) | kk) << 6 | l) << 4));
#pragma unroll
      for (int cg = 0; cg < 4; ++cg)
        acc[cg] = __builtin_amdgcn_mfma_f32_16x16x32_f16(
            Az[kk], Bf[cg], acc[cg], 0, 0, 0);
    }

    // epilogue: s~ = b - acc/1024; pending-min; windowed butterfly
    float sv[4][4];
#pragma unroll
    for (int cg = 0; cg < 4; ++cg)
#pragma unroll
      for (int r = 0; r < 4; ++r)
        sv[cg][r] = __fmaf_rn(acc[cg][r], -0.0009765625f, bc[cg]);
#pragma unroll
    for (int r = 0; r < 4; ++r)
      pmin[r] = fminf(pmin[r],
                      fminf(fminf(sv[0][r], sv[1][r]),
                            fminf(sv[2][r], sv[3][r])));
    const bool doB = (ct == 0) || (ct & 1);
    if (doB) {
#pragma unroll
      for (int m = 1; m < 16; m <<= 1)
#pragma unroll
        for (int r = 0; r < 4; ++r)
          pmin[r] = fminf(pmin[r], __shfl_xor(pmin[r], m, 64));
#pragma unroll
      for (int r = 0; r < 4; ++r) {
        runmin[r] = fminf(runmin[r], pmin[r]);
        pmin[r] = FLT_MAX;
      }
    }
    float thr[4];
    bool anyc = false;
#pragma unroll
    for (int r = 0; r < 4; ++r) {
      thr[r] = fminf(runmin[r], pmin[r]) + MGN;
#pragma unroll
      for (int cg = 0; cg < 4; ++cg) anyc |= (sv[cg][r] <= thr[r]);
    }
    if (__any(anyc)) {
#pragma unroll
      for (int cg = 0; cg < 4; ++cg)
#pragma unroll
        for (int r = 0; r < 4; ++r)
          if (sv[cg][r] <= thr[r]) {
            const int tokl = wv * 16 + kb * 4 + r;
            const int p = atomicAdd(&s_cnt[tokl], 1);
            if (p < CMAX) {
              s_idx[tokl * CMAX + p] = (ushort)(ct * 64 + cg * 16 + c16);
              s_val[tokl * CMAX + p] = sv[cg][r];
            }
          }
    }
    __syncthreads();
  }

  if (c16 == 0) {
#pragma unroll
    for (int r = 0; r < 4; ++r)
      s_rmin[wv * 16 + kb * 4 + r] = runmin[r];
  }
  __syncthreads();

  if (tid < 128) {
    const int t = blockIdx.x * 128 + tid;
    const int cnt = s_cnt[tid];
    if (cnt > CMAX) {
      gcnt[t] = 1000;  // overflow sentinel -> full-scan fallback
    } else {
      const float thr = s_rmin[tid] + MGN;
      int nk = 0;
      for (int p = 0; p < cnt; ++p)
        if (s_val[tid * CMAX + p] <= thr)
          gcand[(size_t)t * CMAX + nk++] = s_idx[tid * CMAX + p];
      gcnt[t] = nk;
    }
  }
}

// cooperative full scan for overflow tokens (expected ~zero), fused
// histogram. Runs BEFORE k_refgather so poisoned idxF is final there.
__global__ __launch_bounds__(256) void k_fallback(
    const float* __restrict__ z, const float* __restrict__ E,
    const float* __restrict__ a, const float* __restrict__ b,
    const int* __restrict__ gcnt, int* __restrict__ idxF,
    float* __restrict__ out_idx, int* __restrict__ counts) {
  __shared__ float rv[256];
  __shared__ int ri[256];
  const int t0 = blockIdx.x * 512;
  for (int t = t0; t < t0 + 512; ++t) {
    if (gcnt[t] <= CMAX) continue;  // uniform across block
    const float* zp = z + (size_t)t * E_DIM;
    float bv = FLT_MAX;
    int bj = 1 << 30;
    for (int c = threadIdx.x; c < N_E; c += 256) {
      const float m = chain_m(zp, E + (size_t)c * E_DIM);
      const float D = __fsub_rn(__fadd_rn(a[t], b[c]), __fmul_rn(2.0f, m));
      if (D < bv || (D == bv && c < bj)) { bv = D; bj = c; }
    }
    rv[threadIdx.x] = bv;
    ri[threadIdx.x] = bj;
    __syncthreads();
    for (int s = 128; s; s >>= 1) {
      if (threadIdx.x < s) {
        const float ov = rv[threadIdx.x + s];
        const int oj = ri[threadIdx.x + s];
        if (ov < rv[threadIdx.x] ||
            (ov == rv[threadIdx.x] && oj < ri[threadIdx.x])) {
          rv[threadIdx.x] = ov;
          ri[threadIdx.x] = oj;
        }
      }
      __syncthreads();
    }
    if (threadIdx.x == 0) {
      idxF[t] = ri[0];
      out_idx[t] = (float)ri[0];
      atomicAdd(&counts[ri[0]], 1);
    }
    __syncthreads();
  }
}

// ---------------------------------------------------------------------------
// k_refgather: fused exact refine (phase 1, 128 tokens/block) + gather/loss
// (phase 2, same 128 rows). Poisoned tokens read idxF written by k_fallback.
// bestj passed phase1->phase2 via LDS (no global round-trip).
// ---------------------------------------------------------------------------
__global__ __launch_bounds__(256) void k_refgather(
    const float* __restrict__ z, const float* __restrict__ E,
    const float* __restrict__ a, const float* __restrict__ b,
    const int* __restrict__ gcnt, const ushort* __restrict__ gcand,
    int* __restrict__ idxF, float* __restrict__ out_idx,
    int* __restrict__ counts, float* __restrict__ out0,
    double* __restrict__ lossPart) {
  __shared__ int s_bj[128];
  __shared__ double red[256];
  const int tid = threadIdx.x;
  const int t0 = blockIdx.x * 128;

  if (tid < 128) {
    const int t = t0 + tid;
    const int cnt = gcnt[t];
    int bestj;
    if (cnt > CMAX) {
      bestj = idxF[t];                 // finalized by k_fallback
    } else if (cnt == 1) {
      bestj = gcand[(size_t)t * CMAX];
      idxF[t] = bestj;
      out_idx[t] = (float)bestj;
      atomicAdd(&counts[bestj], 1);
    } else {
      float bv = FLT_MAX;
      int bj = 1 << 30;
      const float* zp = z + (size_t)t * E_DIM;
      for (int p = 0; p < cnt; ++p) {
        const int c = gcand[(size_t)t * CMAX + p];
        const float m = chain_m(zp, E + (size_t)c * E_DIM);
        const float D = __fsub_rn(__fadd_rn(a[t], b[c]), __fmul_rn(2.0f, m));
        if (D < bv || (D == bv && c < bj)) { bv = D; bj = c; }
      }
      bestj = bj;
      idxF[t] = bestj;
      out_idx[t] = (float)bestj;
      atomicAdd(&counts[bestj], 1);
    }
    s_bj[tid] = bestj;
  }
  __syncthreads();

  // phase 2: gather z_q, write z_q_st = fl(z + fl(zq - z)), f64 loss partial
  double ls = 0.0;
#pragma unroll 4
  for (int i = 0; i < 32; ++i) {
    const int u = i * 256 + tid;          // 0..8191 float4 units
    const int tl = u >> 6;
    const int d4 = (u & 63) * 4;
    const int c = s_bj[tl];
    const size_t tok = (size_t)t0 + tl;
    const float4 zq = *(const float4*)&E[(size_t)c * E_DIM + d4];
    const float4 zv = *(const float4*)&z[tok * E_DIM + d4];
    float4 o;
    o.x = __fadd_rn(zv.x, __fsub_rn(zq.x, zv.x));
    o.y = __fadd_rn(zv.y, __fsub_rn(zq.y, zv.y));
    o.z = __fadd_rn(zv.z, __fsub_rn(zq.z, zv.z));
    o.w = __fadd_rn(zv.w, __fsub_rn(zq.w, zv.w));
    *(float4*)&out0[tok * E_DIM + d4] = o;
    double dx;
    dx = (double)zq.x - (double)zv.x; ls += dx * dx;
    dx = (double)zq.y - (double)zv.y; ls += dx * dx;
    dx = (double)zq.z - (double)zv.z; ls += dx * dx;
    dx = (double)zq.w - (double)zv.w; ls += dx * dx;
  }
  red[tid] = ls;
  __syncthreads();
  for (int s = 128; s; s >>= 1) {
    if (tid < s) red[tid] += red[tid + s];
    __syncthreads();
  }
  if (tid == 0) lossPart[blockIdx.x] = red[0];
}

__global__ __launch_bounds__(256) void k_final(
    const double* __restrict__ lossPart, const int* __restrict__ counts,
    float* __restrict__ outLoss, float* __restrict__ outPerp) {
  __shared__ double rs[256], rh[256];
  double s = 0.0, h = 0.0;
  for (int j = threadIdx.x; j < 512; j += 256) s += lossPart[j];
  for (int j = threadIdx.x; j < N_E; j += 256) {
    const double p = (double)counts[j] * (1.0 / (double)N_TOK);
    h -= p * log(p + 1e-10);
  }
  rs[threadIdx.x] = s;
  rh[threadIdx.x] = h;
  __syncthreads();
  for (int m = 128; m; m >>= 1) {
    if (threadIdx.x < m) {
      rs[threadIdx.x] += rs[threadIdx.x + m];
      rh[threadIdx.x] += rh[threadIdx.x + m];
    }
    __syncthreads();
  }
  if (threadIdx.x == 0) {
    outLoss[0] = (float)((1.0 + BETA) * rs[0] / (double)((size_t)N_TOK * E_DIM));
    outPerp[0] = (float)exp(rh[0]);
  }
}

extern "C" void kernel_launch(void* const* d_in, const int* in_sizes, int n_in,
                              void* d_out, int out_size, void* d_ws, size_t ws_size,
                              hipStream_t stream) {
  const float* z = (const float*)d_in[0];
  const float* E = (const float*)d_in[1];

  float* out0 = (float*)d_out;                       // z_q_st [65536*256]
  float* outLoss = out0 + (size_t)N_TOK * E_DIM;
  float* outPerp = outLoss + 1;
  float* outIdx = outPerp + 1;                       // idx as float [65536]

  char* ws = (char*)d_ws;
  double* lossPart = (double*)(ws + WS_LOSSPART);
  float* a = (float*)(ws + WS_A);
  float* b = (float*)(ws + WS_B);
  int* idxF = (int*)(ws + WS_IDXF);
  int* counts = (int*)(ws + WS_COUNTS);
  int* gcnt = (int*)(ws + WS_CCNT);
  ushort* gcand = (ushort*)(ws + WS_CAND);

  // fp16 operands live in the z_q_st output region (34.6 MB < 64 MB);
  // k_refgather fully overwrites that region afterwards. Deterministic.
  ushort* zf = (ushort*)out0;
  ushort* ef = zf + (size_t)N_TOK * E_DIM;

  (void)hipFuncSetAttribute(reinterpret_cast<const void*>(k_mfma),
                            hipFuncAttributeMaxDynamicSharedMemorySize, 78848);

  hipLaunchKernelGGL(k_prep, dim3(2048), dim3(256), 0, stream,
                     z, E, zf, ef, a, b, counts);
  hipLaunchKernelGGL(k_mfma, dim3(N_TOK / 128), dim3(512), 78848, stream,
                     zf, ef, b, gcnt, gcand);
  hipLaunchKernelGGL(k_fallback, dim3(N_TOK / 512), dim3(256), 0, stream,
                     z, E, a, b, gcnt, idxF, outIdx, counts);
  hipLaunchKernelGGL(k_refgather, dim3(N_TOK / 128), dim3(256), 0, stream,
                     z, E, a, b, gcnt, gcand, idxF, outIdx, counts, out0,
                     lossPart);
  hipLaunchKernelGGL(k_final, dim3(1), dim3(256), 0, stream,
                     lossPart, counts, outLoss, outPerp);
}

// Round 20
// 253.036 us; speedup vs baseline: 1.2919x; 1.2919x over previous
//
#include <hip/hip_runtime.h>
#include <cfloat>
#include <cmath>
#include <cstdint>

#define N_TOK 65536
#define N_E   2048
#define E_DIM 256
#define BETA  0.25

#define MGN 8e-4f     // capture margin; worst-case requirement ~6e-4
#define CMAX 16

// ws layout (bytes)
#define WS_LOSSPART 0          // double[512]     -> 4096
#define WS_A        16384      // float[65536]    -> 278528
#define WS_B        278528     // float[2048]     -> 286720
#define WS_IDXF     286720     // int[65536]      -> 548864
#define WS_COUNTS   548864     // int[2048]       -> 557056
#define WS_CCNT     2654208    // int[65536]      -> 2916352
#define WS_CAND     2916352    // ushort[65536*16]-> 5013504

typedef __attribute__((ext_vector_type(8))) _Float16 half8;
typedef __attribute__((ext_vector_type(4))) float f32x4;

__device__ __forceinline__ ushort f2h(float f) {
  union { _Float16 h; ushort u; } c;
  c.h = (_Float16)f;   // RNE
  return c.u;
}

__device__ __forceinline__ void gload_lds16(const void* g, void* l) {
  __builtin_amdgcn_global_load_lds(
      (const __attribute__((address_space(1))) unsigned int*)(g),
      (__attribute__((address_space(3))) unsigned int*)(l), 16, 0, 0);
}

__device__ __forceinline__ float4 f4add(float4 x, float4 y) {
  float4 r;
  r.x = __fadd_rn(x.x, y.x); r.y = __fadd_rn(x.y, y.y);
  r.z = __fadd_rn(x.z, y.z); r.w = __fadd_rn(x.w, y.w);
  return r;
}

__device__ __forceinline__ float4 f4shfl_xor(float4 x, int m) {
  float4 r;
  r.x = __shfl_xor(x.x, m, 64);
  r.y = __shfl_xor(x.y, m, 64);
  r.z = __shfl_xor(x.z, m, 64);
  r.w = __shfl_xor(x.w, m, 64);
  return r;
}

// exact sequential fused-FMA chain (verified bit-exact vs numpy sgemm, R3)
__device__ __forceinline__ float chain_m(const float* __restrict__ zp,
                                         const float* __restrict__ ep) {
  float acc = 0.f;
  for (int k = 0; k < E_DIM; k += 4) {
    const float4 zz = *(const float4*)(zp + k);
    const float4 ee = *(const float4*)(ep + k);
    acc = __fmaf_rn(zz.x, ee.x, acc);
    acc = __fmaf_rn(zz.y, ee.y, acc);
    acc = __fmaf_rn(zz.z, ee.z, acc);
    acc = __fmaf_rn(zz.w, ee.w, acc);
  }
  return acc;
}

// ---------------------------------------------------------------------------
// k_prep v2 (R18, verified): wave-cooperative coalesced convert + exact
// numpy pairwise tree via shuffles (bit-identical to R3's scalar version).
// ---------------------------------------------------------------------------
__global__ __launch_bounds__(256) void k_prep(
    const float* __restrict__ z, const float* __restrict__ E,
    ushort* __restrict__ zf, ushort* __restrict__ ef,
    float* __restrict__ a, float* __restrict__ b, int* __restrict__ counts) {
  if (blockIdx.x == 0) {
    for (int i = threadIdx.x; i < N_E; i += 256) counts[i] = 0;
  }
  const int l = threadIdx.x & 63;
  const int gw = blockIdx.x * 4 + (threadIdx.x >> 6);   // global wave id
  const int NROW = N_TOK + N_E;                          // 67584 rows

  for (int row = gw; row < NROW; row += 2048 * 4) {
    const bool isZ = row < N_TOK;
    const int lr = isZ ? row : row - N_TOK;
    const float* src = (isZ ? z + (size_t)lr * E_DIM : E + (size_t)lr * E_DIM);
    ushort* dst = (isZ ? zf + (size_t)lr * E_DIM : ef + (size_t)lr * E_DIM);
    const float scale = isZ ? 1.0f : 2048.0f;

    const float4 v = *(const float4*)(src + l * 4);
    ushort4 o;
    o.x = f2h(v.x * scale); o.y = f2h(v.y * scale);
    o.z = f2h(v.z * scale); o.w = f2h(v.w * scale);
    *(ushort4*)(dst + l * 4) = o;

    float4 q;
    q.x = __fmul_rn(v.x, v.x); q.y = __fmul_rn(v.y, v.y);
    q.z = __fmul_rn(v.z, v.z); q.w = __fmul_rn(v.w, v.w);

    float4 s1 = f4add(q, f4shfl_xor(q, 4));
    float4 s2 = f4add(s1, f4shfl_xor(s1, 8));
    float4 s3 = f4add(s2, f4shfl_xor(s2, 16));
    float4 u4 = f4add(s3, f4shfl_xor(s3, 2));
    float4 v4 = f4add(u4, f4shfl_xor(u4, 1));
    const float w0 = __fadd_rn(v4.x, v4.z);
    const float w1 = __fadd_rn(v4.y, v4.w);
    const float blk = __fadd_rn(w0, w1);
    const float other = __shfl_xor(blk, 32, 64);
    const float s = __fadd_rn(blk, other);

    if (l == 0) {
      if (isZ) a[lr] = s; else b[lr] = s;
    }
  }
}

// ---------------------------------------------------------------------------
// MFMA filter v10 (R16/R18, measured 124.7us / 40% occ / 2.2e5 conflicts):
// 512 threads = 8 waves x 16 tokens, grid 512 => 2 blocks/CU, 64KB double-
// buffered B panel in fragment-linear LDS, per-tile FULL wave-wide shuffle-
// min gate (load-bearing — every weakening of it caused poison storms:
// R12/R15/R17/R19), CMAX-16 lists + in-kernel final refilter. FROZEN.
// ---------------------------------------------------------------------------
__global__ __launch_bounds__(512) void k_mfma(
    const ushort* __restrict__ zf, const ushort* __restrict__ ef,
    const float* __restrict__ b, int* __restrict__ gcnt,
    ushort* __restrict__ gcand) {
  extern __shared__ char sm[];
  // [0, 65536): B double buffer (2 x 32 KB, fragment-linear)
  int*    s_cnt  = (int*)(sm + 65536);    // 128 ints
  ushort* s_idx  = (ushort*)(sm + 66048); // 128*16
  float*  s_val  = (float*)(sm + 70144);  // 128*16
  float*  s_rmin = (float*)(sm + 78336);  // 128 floats (end 78848)

  const int tid = threadIdx.x;
  const int wv  = tid >> 6;      // 0..7
  const int l   = tid & 63;
  const int c16 = l & 15;
  const int kb  = l >> 4;
  const int tokBase = blockIdx.x * 128 + wv * 16;

  if (tid < 128) s_cnt[tid] = 0;

  // A fragments: 16 tokens x K=256 (8 chunks of 32), resident in VGPRs
  half8 Az[8];
  {
    const ushort* za = zf + (size_t)(tokBase + c16) * E_DIM + kb * 8;
#pragma unroll
    for (int kk = 0; kk < 8; ++kk) Az[kk] = *(const half8*)(za + kk * 32);
  }

  // prologue: stage panel 0 into buffer 0 (fragment-permuted source)
#pragma unroll
  for (int i = 0; i < 4; ++i) {
    const int g = i * 512 + tid;                 // 16B granule id, 0..2047
    const int cg = g >> 9, kk = (g >> 6) & 7;
    const int cs = g & 15, ks = (g >> 4) & 3;
    gload_lds16(ef + (size_t)(cg * 16 + cs) * E_DIM + kk * 32 + ks * 8,
                sm + g * 16);
  }
  __syncthreads();

  float runmin[4] = {FLT_MAX, FLT_MAX, FLT_MAX, FLT_MAX};

  for (int ct = 0; ct < 32; ++ct) {
    const int cur = ct & 1;
    if (ct + 1 < 32) {
      const ushort* panel = ef + (size_t)(ct + 1) * (64 * E_DIM);
      char* dst = sm + (cur ^ 1) * 32768;
#pragma unroll
      for (int i = 0; i < 4; ++i) {
        const int g = i * 512 + tid;
        const int cg = g >> 9, kk = (g >> 6) & 7;
        const int cs = g & 15, ks = (g >> 4) & 3;
        gload_lds16(panel + (size_t)(cg * 16 + cs) * E_DIM + kk * 32 + ks * 8,
                    dst + g * 16);
      }
    }
    float bc[4];
#pragma unroll
    for (int cg = 0; cg < 4; ++cg) bc[cg] = b[ct * 64 + cg * 16 + c16];

    f32x4 acc[4];
#pragma unroll
    for (int cg = 0; cg < 4; ++cg) acc[cg] = (f32x4){0.f, 0.f, 0.f, 0.f};

    const char* lb = sm + cur * 32768;
#pragma unroll
    for (int kk = 0; kk < 8; ++kk) {
      half8 Bf[4];
#pragma unroll
      for (int cg = 0; cg < 4; ++cg)
        Bf[cg] = *(const half8*)(lb + ((((cg << 3) | kk) << 6 | l) << 4));
#pragma unroll
      for (int cg = 0; cg < 4; ++cg)
        acc[cg] = __builtin_amdgcn_mfma_f32_16x16x32_f16(
            Az[kk], Bf[cg], acc[cg], 0, 0, 0);
    }

    // epilogue: s~ = b - acc/1024, running min + candidate collect
    float sv[4][4];
#pragma unroll
    for (int cg = 0; cg < 4; ++cg)
#pragma unroll
      for (int r = 0; r < 4; ++r)
        sv[cg][r] = __fmaf_rn(acc[cg][r], -0.0009765625f, bc[cg]);
    float tmin[4];
#pragma unroll
    for (int r = 0; r < 4; ++r)
      tmin[r] = fminf(fminf(sv[0][r], sv[1][r]), fminf(sv[2][r], sv[3][r]));
#pragma unroll
    for (int m = 1; m < 16; m <<= 1)
#pragma unroll
      for (int r = 0; r < 4; ++r)
        tmin[r] = fminf(tmin[r], __shfl_xor(tmin[r], m, 64));
    float thr[4];
    bool anyc = false;
#pragma unroll
    for (int r = 0; r < 4; ++r) {
      runmin[r] = fminf(runmin[r], tmin[r]);
      thr[r] = runmin[r] + MGN;
    }
#pragma unroll
    for (int cg = 0; cg < 4; ++cg)
#pragma unroll
      for (int r = 0; r < 4; ++r) anyc |= (sv[cg][r] <= thr[r]);
    if (__any(anyc)) {
#pragma unroll
      for (int cg = 0; cg < 4; ++cg)
#pragma unroll
        for (int r = 0; r < 4; ++r)
          if (sv[cg][r] <= thr[r]) {
            const int tokl = wv * 16 + kb * 4 + r;
            const int p = atomicAdd(&s_cnt[tokl], 1);
            if (p < CMAX) {
              s_idx[tokl * CMAX + p] = (ushort)(ct * 64 + cg * 16 + c16);
              s_val[tokl * CMAX + p] = sv[cg][r];
            }
          }
    }
    __syncthreads();
  }

  if (c16 == 0) {
#pragma unroll
    for (int r = 0; r < 4; ++r)
      s_rmin[wv * 16 + kb * 4 + r] = runmin[r];
  }
  __syncthreads();

  if (tid < 128) {
    const int t = blockIdx.x * 128 + tid;
    const int cnt = s_cnt[tid];
    if (cnt > CMAX) {
      gcnt[t] = 1000;  // overflow sentinel -> full-scan fallback
    } else {
      const float thr = s_rmin[tid] + MGN;
      int nk = 0;
      for (int p = 0; p < cnt; ++p)
        if (s_val[tid * CMAX + p] <= thr)
          gcand[(size_t)t * CMAX + nk++] = s_idx[tid * CMAX + p];
      gcnt[t] = nk;
    }
  }
}

// cooperative full scan for overflow tokens (expected ~zero), fused
// histogram. Runs BEFORE k_refgather so poisoned idxF is final there.
__global__ __launch_bounds__(256) void k_fallback(
    const float* __restrict__ z, const float* __restrict__ E,
    const float* __restrict__ a, const float* __restrict__ b,
    const int* __restrict__ gcnt, int* __restrict__ idxF,
    float* __restrict__ out_idx, int* __restrict__ counts) {
  __shared__ float rv[256];
  __shared__ int ri[256];
  const int t0 = blockIdx.x * 64;
  for (int t = t0; t < t0 + 64; ++t) {
    if (gcnt[t] <= CMAX) continue;  // uniform across block
    const float* zp = z + (size_t)t * E_DIM;
    float bv = FLT_MAX;
    int bj = 1 << 30;
    for (int c = threadIdx.x; c < N_E; c += 256) {
      const float m = chain_m(zp, E + (size_t)c * E_DIM);
      const float D = __fsub_rn(__fadd_rn(a[t], b[c]), __fmul_rn(2.0f, m));
      if (D < bv || (D == bv && c < bj)) { bv = D; bj = c; }
    }
    rv[threadIdx.x] = bv;
    ri[threadIdx.x] = bj;
    __syncthreads();
    for (int s = 128; s; s >>= 1) {
      if (threadIdx.x < s) {
        const float ov = rv[threadIdx.x + s];
        const int oj = ri[threadIdx.x + s];
        if (ov < rv[threadIdx.x] ||
            (ov == rv[threadIdx.x] && oj < ri[threadIdx.x])) {
          rv[threadIdx.x] = ov;
          ri[threadIdx.x] = oj;
        }
      }
      __syncthreads();
    }
    if (threadIdx.x == 0) {
      idxF[t] = ri[0];
      out_idx[t] = (float)ri[0];
      atomicAdd(&counts[ri[0]], 1);
    }
    __syncthreads();
  }
}

// ---------------------------------------------------------------------------
// k_refgather: fused exact refine (phase 1, 128 tokens/block) + gather/loss
// (phase 2, same 128 rows). Poisoned tokens read idxF written by k_fallback.
// bestj passed phase1->phase2 via LDS (no global round-trip). Arithmetic
// bit-identical to R18's separate k_refine + k_gather.
// ---------------------------------------------------------------------------
__global__ __launch_bounds__(256) void k_refgather(
    const float* __restrict__ z, const float* __restrict__ E,
    const float* __restrict__ a, const float* __restrict__ b,
    const int* __restrict__ gcnt, const ushort* __restrict__ gcand,
    int* __restrict__ idxF, float* __restrict__ out_idx,
    int* __restrict__ counts, float* __restrict__ out0,
    double* __restrict__ lossPart) {
  __shared__ int s_bj[128];
  __shared__ double red[256];
  const int tid = threadIdx.x;
  const int t0 = blockIdx.x * 128;

  if (tid < 128) {
    const int t = t0 + tid;
    const int cnt = gcnt[t];
    int bestj;
    if (cnt > CMAX) {
      bestj = idxF[t];                 // finalized by k_fallback
    } else if (cnt == 1) {
      bestj = gcand[(size_t)t * CMAX];
      idxF[t] = bestj;
      out_idx[t] = (float)bestj;
      atomicAdd(&counts[bestj], 1);
    } else {
      float bv = FLT_MAX;
      int bj = 1 << 30;
      const float* zp = z + (size_t)t * E_DIM;
      for (int p = 0; p < cnt; ++p) {
        const int c = gcand[(size_t)t * CMAX + p];
        const float m = chain_m(zp, E + (size_t)c * E_DIM);
        const float D = __fsub_rn(__fadd_rn(a[t], b[c]), __fmul_rn(2.0f, m));
        if (D < bv || (D == bv && c < bj)) { bv = D; bj = c; }
      }
      bestj = bj;
      idxF[t] = bestj;
      out_idx[t] = (float)bestj;
      atomicAdd(&counts[bestj], 1);
    }
    s_bj[tid] = bestj;
  }
  __syncthreads();

  // phase 2: gather z_q, write z_q_st = fl(z + fl(zq - z)), f64 loss partial
  double ls = 0.0;
#pragma unroll 4
  for (int i = 0; i < 32; ++i) {
    const int u = i * 256 + tid;          // 0..8191 float4 units
    const int tl = u >> 6;
    const int d4 = (u & 63) * 4;
    const int c = s_bj[tl];
    const size_t tok = (size_t)t0 + tl;
    const float4 zq = *(const float4*)&E[(size_t)c * E_DIM + d4];
    const float4 zv = *(const float4*)&z[tok * E_DIM + d4];
    float4 o;
    o.x = __fadd_rn(zv.x, __fsub_rn(zq.x, zv.x));
    o.y = __fadd_rn(zv.y, __fsub_rn(zq.y, zv.y));
    o.z = __fadd_rn(zv.z, __fsub_rn(zq.z, zv.z));
    o.w = __fadd_rn(zv.w, __fsub_rn(zq.w, zv.w));
    *(float4*)&out0[tok * E_DIM + d4] = o;
    double dx;
    dx = (double)zq.x - (double)zv.x; ls += dx * dx;
    dx = (double)zq.y - (double)zv.y; ls += dx * dx;
    dx = (double)zq.z - (double)zv.z; ls += dx * dx;
    dx = (double)zq.w - (double)zv.w; ls += dx * dx;
  }
  red[tid] = ls;
  __syncthreads();
  for (int s = 128; s; s >>= 1) {
    if (tid < s) red[tid] += red[tid + s];
    __syncthreads();
  }
  if (tid == 0) lossPart[blockIdx.x] = red[0];
}

__global__ __launch_bounds__(256) void k_final(
    const double* __restrict__ lossPart, const int* __restrict__ counts,
    float* __restrict__ outLoss, float* __restrict__ outPerp) {
  __shared__ double rs[256], rh[256];
  double s = 0.0, h = 0.0;
  for (int j = threadIdx.x; j < 512; j += 256) s += lossPart[j];
  for (int j = threadIdx.x; j < N_E; j += 256) {
    const double p = (double)counts[j] * (1.0 / (double)N_TOK);
    h -= p * log(p + 1e-10);
  }
  rs[threadIdx.x] = s;
  rh[threadIdx.x] = h;
  __syncthreads();
  for (int m = 128; m; m >>= 1) {
    if (threadIdx.x < m) {
      rs[threadIdx.x] += rs[threadIdx.x + m];
      rh[threadIdx.x] += rh[threadIdx.x + m];
    }
    __syncthreads();
  }
  if (threadIdx.x == 0) {
    outLoss[0] = (float)((1.0 + BETA) * rs[0] / (double)((size_t)N_TOK * E_DIM));
    outPerp[0] = (float)exp(rh[0]);
  }
}

extern "C" void kernel_launch(void* const* d_in, const int* in_sizes, int n_in,
                              void* d_out, int out_size, void* d_ws, size_t ws_size,
                              hipStream_t stream) {
  const float* z = (const float*)d_in[0];
  const float* E = (const float*)d_in[1];

  float* out0 = (float*)d_out;                       // z_q_st [65536*256]
  float* outLoss = out0 + (size_t)N_TOK * E_DIM;
  float* outPerp = outLoss + 1;
  float* outIdx = outPerp + 1;                       // idx as float [65536]

  char* ws = (char*)d_ws;
  double* lossPart = (double*)(ws + WS_LOSSPART);
  float* a = (float*)(ws + WS_A);
  float* b = (float*)(ws + WS_B);
  int* idxF = (int*)(ws + WS_IDXF);
  int* counts = (int*)(ws + WS_COUNTS);
  int* gcnt = (int*)(ws + WS_CCNT);
  ushort* gcand = (ushort*)(ws + WS_CAND);

  // fp16 operands live in the z_q_st output region (34.6 MB < 64 MB);
  // k_refgather fully overwrites that region afterwards. Deterministic.
  ushort* zf = (ushort*)out0;
  ushort* ef = zf + (size_t)N_TOK * E_DIM;

  (void)hipFuncSetAttribute(reinterpret_cast<const void*>(k_mfma),
                            hipFuncAttributeMaxDynamicSharedMemorySize, 78848);

  hipLaunchKernelGGL(k_prep, dim3(2048), dim3(256), 0, stream,
                     z, E, zf, ef, a, b, counts);
  hipLaunchKernelGGL(k_mfma, dim3(N_TOK / 128), dim3(512), 78848, stream,
                     zf, ef, b, gcnt, gcand);
  hipLaunchKernelGGL(k_fallback, dim3(N_TOK / 64), dim3(256), 0, stream,
                     z, E, a, b, gcnt, idxF, outIdx, counts);
  hipLaunchKernelGGL(k_refgather, dim3(N_TOK / 128), dim3(256), 0, stream,
                     z, E, a, b, gcnt, gcand, idxF, outIdx, counts, out0,
                     lossPart);
  hipLaunchKernelGGL(k_final, dim3(1), dim3(256), 0, stream,
                     lossPart, counts, outLoss, outPerp);
}

// Round 21
// 250.328 us; speedup vs baseline: 1.3059x; 1.0108x over previous
//
#include <hip/hip_runtime.h>
#include <cfloat>
#include <cmath>
#include <cstdint>

#define N_TOK 65536
#define N_E   2048
#define E_DIM 256
#define BETA  0.25

#define MGN 8e-4f     // capture margin; worst-case requirement ~6e-4
#define CMAX 16

// ws layout (bytes)
#define WS_LOSSPART 0          // double[512]     -> 4096
#define WS_A        16384      // float[65536]    -> 278528
#define WS_B        278528     // float[2048]     -> 286720
#define WS_IDXF     286720     // int[65536]      -> 548864
#define WS_COUNTS   548864     // int[2048]       -> 557056
#define WS_CCNT     2654208    // int[65536]      -> 2916352
#define WS_CAND     2916352    // ushort[65536*16]-> 5013504

typedef __attribute__((ext_vector_type(8))) _Float16 half8;
typedef __attribute__((ext_vector_type(4))) float f32x4;

__device__ __forceinline__ ushort f2h(float f) {
  union { _Float16 h; ushort u; } c;
  c.h = (_Float16)f;   // RNE
  return c.u;
}

__device__ __forceinline__ void gload_lds16(const void* g, void* l) {
  __builtin_amdgcn_global_load_lds(
      (const __attribute__((address_space(1))) unsigned int*)(g),
      (__attribute__((address_space(3))) unsigned int*)(l), 16, 0, 0);
}

__device__ __forceinline__ float4 f4add(float4 x, float4 y) {
  float4 r;
  r.x = __fadd_rn(x.x, y.x); r.y = __fadd_rn(x.y, y.y);
  r.z = __fadd_rn(x.z, y.z); r.w = __fadd_rn(x.w, y.w);
  return r;
}

__device__ __forceinline__ float4 f4shfl_xor(float4 x, int m) {
  float4 r;
  r.x = __shfl_xor(x.x, m, 64);
  r.y = __shfl_xor(x.y, m, 64);
  r.z = __shfl_xor(x.z, m, 64);
  r.w = __shfl_xor(x.w, m, 64);
  return r;
}

// exact sequential fused-FMA chain (verified bit-exact vs numpy sgemm, R3)
__device__ __forceinline__ float chain_m(const float* __restrict__ zp,
                                         const float* __restrict__ ep) {
  float acc = 0.f;
  for (int k = 0; k < E_DIM; k += 4) {
    const float4 zz = *(const float4*)(zp + k);
    const float4 ee = *(const float4*)(ep + k);
    acc = __fmaf_rn(zz.x, ee.x, acc);
    acc = __fmaf_rn(zz.y, ee.y, acc);
    acc = __fmaf_rn(zz.z, ee.z, acc);
    acc = __fmaf_rn(zz.w, ee.w, acc);
  }
  return acc;
}

// ---------------------------------------------------------------------------
// k_prep v2 (R18, verified): wave-cooperative coalesced convert + exact
// numpy pairwise tree via shuffles (bit-identical to R3's scalar version).
// ---------------------------------------------------------------------------
__global__ __launch_bounds__(256) void k_prep(
    const float* __restrict__ z, const float* __restrict__ E,
    ushort* __restrict__ zf, ushort* __restrict__ ef,
    float* __restrict__ a, float* __restrict__ b, int* __restrict__ counts) {
  if (blockIdx.x == 0) {
    for (int i = threadIdx.x; i < N_E; i += 256) counts[i] = 0;
  }
  const int l = threadIdx.x & 63;
  const int gw = blockIdx.x * 4 + (threadIdx.x >> 6);   // global wave id
  const int NROW = N_TOK + N_E;                          // 67584 rows

  for (int row = gw; row < NROW; row += 2048 * 4) {
    const bool isZ = row < N_TOK;
    const int lr = isZ ? row : row - N_TOK;
    const float* src = (isZ ? z + (size_t)lr * E_DIM : E + (size_t)lr * E_DIM);
    ushort* dst = (isZ ? zf + (size_t)lr * E_DIM : ef + (size_t)lr * E_DIM);
    const float scale = isZ ? 1.0f : 2048.0f;

    const float4 v = *(const float4*)(src + l * 4);
    ushort4 o;
    o.x = f2h(v.x * scale); o.y = f2h(v.y * scale);
    o.z = f2h(v.z * scale); o.w = f2h(v.w * scale);
    *(ushort4*)(dst + l * 4) = o;

    float4 q;
    q.x = __fmul_rn(v.x, v.x); q.y = __fmul_rn(v.y, v.y);
    q.z = __fmul_rn(v.z, v.z); q.w = __fmul_rn(v.w, v.w);

    float4 s1 = f4add(q, f4shfl_xor(q, 4));
    float4 s2 = f4add(s1, f4shfl_xor(s1, 8));
    float4 s3 = f4add(s2, f4shfl_xor(s2, 16));
    float4 u4 = f4add(s3, f4shfl_xor(s3, 2));
    float4 v4 = f4add(u4, f4shfl_xor(u4, 1));
    const float w0 = __fadd_rn(v4.x, v4.z);
    const float w1 = __fadd_rn(v4.y, v4.w);
    const float blk = __fadd_rn(w0, w1);
    const float other = __shfl_xor(blk, 32, 64);
    const float s = __fadd_rn(blk, other);

    if (l == 0) {
      if (isZ) a[lr] = s; else b[lr] = s;
    }
  }
}

// ---------------------------------------------------------------------------
// MFMA filter v10 (R16/R18/R20, measured 124.7us / 40% occ / 2.2e5
// conflicts): 512 threads = 8 waves x 16 tokens, grid 512 => 2 blocks/CU,
// 64KB double-buffered B panel in fragment-linear LDS, per-tile FULL
// wave-wide shuffle-min gate (load-bearing — every weakening caused poison
// storms: R12/R15/R17/R19), CMAX-16 lists + in-kernel final refilter.
// FROZEN.
// ---------------------------------------------------------------------------
__global__ __launch_bounds__(512) void k_mfma(
    const ushort* __restrict__ zf, const ushort* __restrict__ ef,
    const float* __restrict__ b, int* __restrict__ gcnt,
    ushort* __restrict__ gcand) {
  extern __shared__ char sm[];
  // [0, 65536): B double buffer (2 x 32 KB, fragment-linear)
  int*    s_cnt  = (int*)(sm + 65536);    // 128 ints
  ushort* s_idx  = (ushort*)(sm + 66048); // 128*16
  float*  s_val  = (float*)(sm + 70144);  // 128*16
  float*  s_rmin = (float*)(sm + 78336);  // 128 floats (end 78848)

  const int tid = threadIdx.x;
  const int wv  = tid >> 6;      // 0..7
  const int l   = tid & 63;
  const int c16 = l & 15;
  const int kb  = l >> 4;
  const int tokBase = blockIdx.x * 128 + wv * 16;

  if (tid < 128) s_cnt[tid] = 0;

  // A fragments: 16 tokens x K=256 (8 chunks of 32), resident in VGPRs
  half8 Az[8];
  {
    const ushort* za = zf + (size_t)(tokBase + c16) * E_DIM + kb * 8;
#pragma unroll
    for (int kk = 0; kk < 8; ++kk) Az[kk] = *(const half8*)(za + kk * 32);
  }

  // prologue: stage panel 0 into buffer 0 (fragment-permuted source)
#pragma unroll
  for (int i = 0; i < 4; ++i) {
    const int g = i * 512 + tid;                 // 16B granule id, 0..2047
    const int cg = g >> 9, kk = (g >> 6) & 7;
    const int cs = g & 15, ks = (g >> 4) & 3;
    gload_lds16(ef + (size_t)(cg * 16 + cs) * E_DIM + kk * 32 + ks * 8,
                sm + g * 16);
  }
  __syncthreads();

  float runmin[4] = {FLT_MAX, FLT_MAX, FLT_MAX, FLT_MAX};

  for (int ct = 0; ct < 32; ++ct) {
    const int cur = ct & 1;
    if (ct + 1 < 32) {
      const ushort* panel = ef + (size_t)(ct + 1) * (64 * E_DIM);
      char* dst = sm + (cur ^ 1) * 32768;
#pragma unroll
      for (int i = 0; i < 4; ++i) {
        const int g = i * 512 + tid;
        const int cg = g >> 9, kk = (g >> 6) & 7;
        const int cs = g & 15, ks = (g >> 4) & 3;
        gload_lds16(panel + (size_t)(cg * 16 + cs) * E_DIM + kk * 32 + ks * 8,
                    dst + g * 16);
      }
    }
    float bc[4];
#pragma unroll
    for (int cg = 0; cg < 4; ++cg) bc[cg] = b[ct * 64 + cg * 16 + c16];

    f32x4 acc[4];
#pragma unroll
    for (int cg = 0; cg < 4; ++cg) acc[cg] = (f32x4){0.f, 0.f, 0.f, 0.f};

    const char* lb = sm + cur * 32768;
#pragma unroll
    for (int kk = 0; kk < 8; ++kk) {
      half8 Bf[4];
#pragma unroll
      for (int cg = 0; cg < 4; ++cg)
        Bf[cg] = *(const half8*)(lb + ((((cg << 3) | kk) << 6 | l) << 4));
#pragma unroll
      for (int cg = 0; cg < 4; ++cg)
        acc[cg] = __builtin_amdgcn_mfma_f32_16x16x32_f16(
            Az[kk], Bf[cg], acc[cg], 0, 0, 0);
    }

    // epilogue: s~ = b - acc/1024, running min + candidate collect
    float sv[4][4];
#pragma unroll
    for (int cg = 0; cg < 4; ++cg)
#pragma unroll
      for (int r = 0; r < 4; ++r)
        sv[cg][r] = __fmaf_rn(acc[cg][r], -0.0009765625f, bc[cg]);
    float tmin[4];
#pragma unroll
    for (int r = 0; r < 4; ++r)
      tmin[r] = fminf(fminf(sv[0][r], sv[1][r]), fminf(sv[2][r], sv[3][r]));
#pragma unroll
    for (int m = 1; m < 16; m <<= 1)
#pragma unroll
      for (int r = 0; r < 4; ++r)
        tmin[r] = fminf(tmin[r], __shfl_xor(tmin[r], m, 64));
    float thr[4];
    bool anyc = false;
#pragma unroll
    for (int r = 0; r < 4; ++r) {
      runmin[r] = fminf(runmin[r], tmin[r]);
      thr[r] = runmin[r] + MGN;
    }
#pragma unroll
    for (int cg = 0; cg < 4; ++cg)
#pragma unroll
      for (int r = 0; r < 4; ++r) anyc |= (sv[cg][r] <= thr[r]);
    if (__any(anyc)) {
#pragma unroll
      for (int cg = 0; cg < 4; ++cg)
#pragma unroll
        for (int r = 0; r < 4; ++r)
          if (sv[cg][r] <= thr[r]) {
            const int tokl = wv * 16 + kb * 4 + r;
            const int p = atomicAdd(&s_cnt[tokl], 1);
            if (p < CMAX) {
              s_idx[tokl * CMAX + p] = (ushort)(ct * 64 + cg * 16 + c16);
              s_val[tokl * CMAX + p] = sv[cg][r];
            }
          }
    }
    __syncthreads();
  }

  if (c16 == 0) {
#pragma unroll
    for (int r = 0; r < 4; ++r)
      s_rmin[wv * 16 + kb * 4 + r] = runmin[r];
  }
  __syncthreads();

  if (tid < 128) {
    const int t = blockIdx.x * 128 + tid;
    const int cnt = s_cnt[tid];
    if (cnt > CMAX) {
      gcnt[t] = 1000;  // overflow sentinel -> full-scan fallback
    } else {
      const float thr = s_rmin[tid] + MGN;
      int nk = 0;
      for (int p = 0; p < cnt; ++p)
        if (s_val[tid * CMAX + p] <= thr)
          gcand[(size_t)t * CMAX + nk++] = s_idx[tid * CMAX + p];
      gcnt[t] = nk;
    }
  }
}

// cooperative full scan for overflow tokens (expected ~zero), fused
// histogram. Runs BEFORE k_refgather so poisoned idxF is final there.
__global__ __launch_bounds__(256) void k_fallback(
    const float* __restrict__ z, const float* __restrict__ E,
    const float* __restrict__ a, const float* __restrict__ b,
    const int* __restrict__ gcnt, int* __restrict__ idxF,
    float* __restrict__ out_idx, int* __restrict__ counts) {
  __shared__ float rv[256];
  __shared__ int ri[256];
  const int t0 = blockIdx.x * 64;
  for (int t = t0; t < t0 + 64; ++t) {
    if (gcnt[t] <= CMAX) continue;  // uniform across block
    const float* zp = z + (size_t)t * E_DIM;
    float bv = FLT_MAX;
    int bj = 1 << 30;
    for (int c = threadIdx.x; c < N_E; c += 256) {
      const float m = chain_m(zp, E + (size_t)c * E_DIM);
      const float D = __fsub_rn(__fadd_rn(a[t], b[c]), __fmul_rn(2.0f, m));
      if (D < bv || (D == bv && c < bj)) { bv = D; bj = c; }
    }
    rv[threadIdx.x] = bv;
    ri[threadIdx.x] = bj;
    __syncthreads();
    for (int s = 128; s; s >>= 1) {
      if (threadIdx.x < s) {
        const float ov = rv[threadIdx.x + s];
        const int oj = ri[threadIdx.x + s];
        if (ov < rv[threadIdx.x] ||
            (ov == rv[threadIdx.x] && oj < ri[threadIdx.x])) {
          rv[threadIdx.x] = ov;
          ri[threadIdx.x] = oj;
        }
      }
      __syncthreads();
    }
    if (threadIdx.x == 0) {
      idxF[t] = ri[0];
      out_idx[t] = (float)ri[0];
      atomicAdd(&counts[ri[0]], 1);
    }
    __syncthreads();
  }
}

// ---------------------------------------------------------------------------
// k_refgather v2: phase 1 now uses ALL 256 threads — 2 threads per token,
// candidate list split by parity (p = sub, sub+2, ...), local lexicographic
// (D, idx) min, pair-combined via one shfl_xor(1) (pairs are intra-wave).
// Lex-min is associative/commutative over (D,idx) pairs and each candidate's
// D comes from the identical exact chain => bit-identical to R20's serial
// version. Phase 2 (gather + f64 loss) unchanged.
// ---------------------------------------------------------------------------
__global__ __launch_bounds__(256) void k_refgather(
    const float* __restrict__ z, const float* __restrict__ E,
    const float* __restrict__ a, const float* __restrict__ b,
    const int* __restrict__ gcnt, const ushort* __restrict__ gcand,
    int* __restrict__ idxF, float* __restrict__ out_idx,
    int* __restrict__ counts, float* __restrict__ out0,
    double* __restrict__ lossPart) {
  __shared__ int s_bj[128];
  __shared__ double red[256];
  const int tid = threadIdx.x;
  const int t0 = blockIdx.x * 128;

  {
    const int tl = tid >> 1;          // token within block, 0..127
    const int sub = tid & 1;          // candidate-parity lane of the pair
    const int t = t0 + tl;
    const int cnt = gcnt[t];
    int bestj;
    if (cnt > CMAX) {
      bestj = idxF[t];                // finalized by k_fallback
    } else if (cnt == 1) {
      bestj = gcand[(size_t)t * CMAX];
    } else {
      float bv = FLT_MAX;
      int bj = 1 << 30;
      const float* zp = z + (size_t)t * E_DIM;
      for (int p = sub; p < cnt; p += 2) {
        const int c = gcand[(size_t)t * CMAX + p];
        const float m = chain_m(zp, E + (size_t)c * E_DIM);
        const float D = __fsub_rn(__fadd_rn(a[t], b[c]), __fmul_rn(2.0f, m));
        if (D < bv || (D == bv && c < bj)) { bv = D; bj = c; }
      }
      const float ov = __shfl_xor(bv, 1, 64);
      const int oj = __shfl_xor(bj, 1, 64);
      if (ov < bv || (ov == bv && oj < bj)) { bv = ov; bj = oj; }
      bestj = bj;
    }
    if (sub == 0) {
      s_bj[tl] = bestj;
      if (cnt <= CMAX) {              // poisoned tokens already written
        idxF[t] = bestj;
        out_idx[t] = (float)bestj;
        atomicAdd(&counts[bestj], 1);
      }
    }
  }
  __syncthreads();

  // phase 2: gather z_q, write z_q_st = fl(z + fl(zq - z)), f64 loss partial
  double ls = 0.0;
#pragma unroll 4
  for (int i = 0; i < 32; ++i) {
    const int u = i * 256 + tid;          // 0..8191 float4 units
    const int tl = u >> 6;
    const int d4 = (u & 63) * 4;
    const int c = s_bj[tl];
    const size_t tok = (size_t)t0 + tl;
    const float4 zq = *(const float4*)&E[(size_t)c * E_DIM + d4];
    const float4 zv = *(const float4*)&z[tok * E_DIM + d4];
    float4 o;
    o.x = __fadd_rn(zv.x, __fsub_rn(zq.x, zv.x));
    o.y = __fadd_rn(zv.y, __fsub_rn(zq.y, zv.y));
    o.z = __fadd_rn(zv.z, __fsub_rn(zq.z, zv.z));
    o.w = __fadd_rn(zv.w, __fsub_rn(zq.w, zv.w));
    *(float4*)&out0[tok * E_DIM + d4] = o;
    double dx;
    dx = (double)zq.x - (double)zv.x; ls += dx * dx;
    dx = (double)zq.y - (double)zv.y; ls += dx * dx;
    dx = (double)zq.z - (double)zv.z; ls += dx * dx;
    dx = (double)zq.w - (double)zv.w; ls += dx * dx;
  }
  red[tid] = ls;
  __syncthreads();
  for (int s = 128; s; s >>= 1) {
    if (tid < s) red[tid] += red[tid + s];
    __syncthreads();
  }
  if (tid == 0) lossPart[blockIdx.x] = red[0];
}

__global__ __launch_bounds__(256) void k_final(
    const double* __restrict__ lossPart, const int* __restrict__ counts,
    float* __restrict__ outLoss, float* __restrict__ outPerp) {
  __shared__ double rs[256], rh[256];
  double s = 0.0, h = 0.0;
  for (int j = threadIdx.x; j < 512; j += 256) s += lossPart[j];
  for (int j = threadIdx.x; j < N_E; j += 256) {
    const double p = (double)counts[j] * (1.0 / (double)N_TOK);
    h -= p * log(p + 1e-10);
  }
  rs[threadIdx.x] = s;
  rh[threadIdx.x] = h;
  __syncthreads();
  for (int m = 128; m; m >>= 1) {
    if (threadIdx.x < m) {
      rs[threadIdx.x] += rs[threadIdx.x + m];
      rh[threadIdx.x] += rh[threadIdx.x + m];
    }
    __syncthreads();
  }
  if (threadIdx.x == 0) {
    outLoss[0] = (float)((1.0 + BETA) * rs[0] / (double)((size_t)N_TOK * E_DIM));
    outPerp[0] = (float)exp(rh[0]);
  }
}

extern "C" void kernel_launch(void* const* d_in, const int* in_sizes, int n_in,
                              void* d_out, int out_size, void* d_ws, size_t ws_size,
                              hipStream_t stream) {
  const float* z = (const float*)d_in[0];
  const float* E = (const float*)d_in[1];

  float* out0 = (float*)d_out;                       // z_q_st [65536*256]
  float* outLoss = out0 + (size_t)N_TOK * E_DIM;
  float* outPerp = outLoss + 1;
  float* outIdx = outPerp + 1;                       // idx as float [65536]

  char* ws = (char*)d_ws;
  double* lossPart = (double*)(ws + WS_LOSSPART);
  float* a = (float*)(ws + WS_A);
  float* b = (float*)(ws + WS_B);
  int* idxF = (int*)(ws + WS_IDXF);
  int* counts = (int*)(ws + WS_COUNTS);
  int* gcnt = (int*)(ws + WS_CCNT);
  ushort* gcand = (ushort*)(ws + WS_CAND);

  // fp16 operands live in the z_q_st output region (34.6 MB < 64 MB);
  // k_refgather fully overwrites that region afterwards. Deterministic.
  ushort* zf = (ushort*)out0;
  ushort* ef = zf + (size_t)N_TOK * E_DIM;

  (void)hipFuncSetAttribute(reinterpret_cast<const void*>(k_mfma),
                            hipFuncAttributeMaxDynamicSharedMemorySize, 78848);

  hipLaunchKernelGGL(k_prep, dim3(2048), dim3(256), 0, stream,
                     z, E, zf, ef, a, b, counts);
  hipLaunchKernelGGL(k_mfma, dim3(N_TOK / 128), dim3(512), 78848, stream,
                     zf, ef, b, gcnt, gcand);
  hipLaunchKernelGGL(k_fallback, dim3(N_TOK / 64), dim3(256), 0, stream,
                     z, E, a, b, gcnt, idxF, outIdx, counts);
  hipLaunchKernelGGL(k_refgather, dim3(N_TOK / 128), dim3(256), 0, stream,
                     z, E, a, b, gcnt, gcand, idxF, outIdx, counts, out0,
                     lossPart);
  hipLaunchKernelGGL(k_final, dim3(1), dim3(256), 0, stream,
                     lossPart, counts, outLoss, outPerp);
}

// Round 22
// 236.770 us; speedup vs baseline: 1.3806x; 1.0573x over previous
//
#include <hip/hip_runtime.h>
#include <cfloat>
#include <cmath>
#include <cstdint>

#define N_TOK 65536
#define N_E   2048
#define E_DIM 256
#define BETA  0.25

#define MGN 8e-4f     // capture margin; worst-case requirement ~6e-4
#define CMAX 16

// ws layout (bytes)
#define WS_LOSSPART 0          // double[512]     -> 4096
#define WS_A        16384      // float[65536]    -> 278528
#define WS_B        278528     // float[2048]     -> 286720
#define WS_IDXF     286720     // int[65536]      -> 548864
#define WS_COUNTS   548864     // int[2048]       -> 557056
#define WS_CCNT     2654208    // int[65536]      -> 2916352
#define WS_CAND     2916352    // ushort[65536*16]-> 5013504

typedef __attribute__((ext_vector_type(8))) _Float16 half8;
typedef __attribute__((ext_vector_type(4))) float f32x4;

__device__ __forceinline__ ushort f2h(float f) {
  union { _Float16 h; ushort u; } c;
  c.h = (_Float16)f;   // RNE
  return c.u;
}

__device__ __forceinline__ void gload_lds16(const void* g, void* l) {
  __builtin_amdgcn_global_load_lds(
      (const __attribute__((address_space(1))) unsigned int*)(g),
      (__attribute__((address_space(3))) unsigned int*)(l), 16, 0, 0);
}

__device__ __forceinline__ float4 f4add(float4 x, float4 y) {
  float4 r;
  r.x = __fadd_rn(x.x, y.x); r.y = __fadd_rn(x.y, y.y);
  r.z = __fadd_rn(x.z, y.z); r.w = __fadd_rn(x.w, y.w);
  return r;
}

__device__ __forceinline__ float4 f4shfl_xor(float4 x, int m) {
  float4 r;
  r.x = __shfl_xor(x.x, m, 64);
  r.y = __shfl_xor(x.y, m, 64);
  r.z = __shfl_xor(x.z, m, 64);
  r.w = __shfl_xor(x.w, m, 64);
  return r;
}

// exact sequential fused-FMA chain (verified bit-exact vs numpy sgemm, R3)
__device__ __forceinline__ float chain_m(const float* __restrict__ zp,
                                         const float* __restrict__ ep) {
  float acc = 0.f;
  for (int k = 0; k < E_DIM; k += 4) {
    const float4 zz = *(const float4*)(zp + k);
    const float4 ee = *(const float4*)(ep + k);
    acc = __fmaf_rn(zz.x, ee.x, acc);
    acc = __fmaf_rn(zz.y, ee.y, acc);
    acc = __fmaf_rn(zz.z, ee.z, acc);
    acc = __fmaf_rn(zz.w, ee.w, acc);
  }
  return acc;
}

// ---------------------------------------------------------------------------
// k_prep v2 (R18, verified): wave-cooperative coalesced convert + exact
// numpy pairwise tree via shuffles (bit-identical to R3's scalar version).
// ---------------------------------------------------------------------------
__global__ __launch_bounds__(256) void k_prep(
    const float* __restrict__ z, const float* __restrict__ E,
    ushort* __restrict__ zf, ushort* __restrict__ ef,
    float* __restrict__ a, float* __restrict__ b, int* __restrict__ counts) {
  if (blockIdx.x == 0) {
    for (int i = threadIdx.x; i < N_E; i += 256) counts[i] = 0;
  }
  const int l = threadIdx.x & 63;
  const int gw = blockIdx.x * 4 + (threadIdx.x >> 6);   // global wave id
  const int NROW = N_TOK + N_E;                          // 67584 rows

  for (int row = gw; row < NROW; row += 2048 * 4) {
    const bool isZ = row < N_TOK;
    const int lr = isZ ? row : row - N_TOK;
    const float* src = (isZ ? z + (size_t)lr * E_DIM : E + (size_t)lr * E_DIM);
    ushort* dst = (isZ ? zf + (size_t)lr * E_DIM : ef + (size_t)lr * E_DIM);
    const float scale = isZ ? 1.0f : 2048.0f;

    const float4 v = *(const float4*)(src + l * 4);
    ushort4 o;
    o.x = f2h(v.x * scale); o.y = f2h(v.y * scale);
    o.z = f2h(v.z * scale); o.w = f2h(v.w * scale);
    *(ushort4*)(dst + l * 4) = o;

    float4 q;
    q.x = __fmul_rn(v.x, v.x); q.y = __fmul_rn(v.y, v.y);
    q.z = __fmul_rn(v.z, v.z); q.w = __fmul_rn(v.w, v.w);

    float4 s1 = f4add(q, f4shfl_xor(q, 4));
    float4 s2 = f4add(s1, f4shfl_xor(s1, 8));
    float4 s3 = f4add(s2, f4shfl_xor(s2, 16));
    float4 u4 = f4add(s3, f4shfl_xor(s3, 2));
    float4 v4 = f4add(u4, f4shfl_xor(u4, 1));
    const float w0 = __fadd_rn(v4.x, v4.z);
    const float w1 = __fadd_rn(v4.y, v4.w);
    const float blk = __fadd_rn(w0, w1);
    const float other = __shfl_xor(blk, 32, 64);
    const float s = __fadd_rn(blk, other);

    if (l == 0) {
      if (isZ) a[lr] = s; else b[lr] = s;
    }
  }
}

// ---------------------------------------------------------------------------
// MFMA filter v10 (R16/R18/R20/R21, measured 125us / 41% occ / 2.2e5
// conflicts): 512 threads = 8 waves x 16 tokens, grid 512 => 2 blocks/CU,
// 64KB double-buffered B panel in fragment-linear LDS, per-tile FULL
// wave-wide shuffle-min gate (load-bearing — every weakening caused poison
// storms: R12/R15/R17/R19), CMAX-16 lists + in-kernel final refilter.
// FROZEN.
// ---------------------------------------------------------------------------
__global__ __launch_bounds__(512) void k_mfma(
    const ushort* __restrict__ zf, const ushort* __restrict__ ef,
    const float* __restrict__ b, int* __restrict__ gcnt,
    ushort* __restrict__ gcand) {
  extern __shared__ char sm[];
  // [0, 65536): B double buffer (2 x 32 KB, fragment-linear)
  int*    s_cnt  = (int*)(sm + 65536);    // 128 ints
  ushort* s_idx  = (ushort*)(sm + 66048); // 128*16
  float*  s_val  = (float*)(sm + 70144);  // 128*16
  float*  s_rmin = (float*)(sm + 78336);  // 128 floats (end 78848)

  const int tid = threadIdx.x;
  const int wv  = tid >> 6;      // 0..7
  const int l   = tid & 63;
  const int c16 = l & 15;
  const int kb  = l >> 4;
  const int tokBase = blockIdx.x * 128 + wv * 16;

  if (tid < 128) s_cnt[tid] = 0;

  // A fragments: 16 tokens x K=256 (8 chunks of 32), resident in VGPRs
  half8 Az[8];
  {
    const ushort* za = zf + (size_t)(tokBase + c16) * E_DIM + kb * 8;
#pragma unroll
    for (int kk = 0; kk < 8; ++kk) Az[kk] = *(const half8*)(za + kk * 32);
  }

  // prologue: stage panel 0 into buffer 0 (fragment-permuted source)
#pragma unroll
  for (int i = 0; i < 4; ++i) {
    const int g = i * 512 + tid;                 // 16B granule id, 0..2047
    const int cg = g >> 9, kk = (g >> 6) & 7;
    const int cs = g & 15, ks = (g >> 4) & 3;
    gload_lds16(ef + (size_t)(cg * 16 + cs) * E_DIM + kk * 32 + ks * 8,
                sm + g * 16);
  }
  __syncthreads();

  float runmin[4] = {FLT_MAX, FLT_MAX, FLT_MAX, FLT_MAX};

  for (int ct = 0; ct < 32; ++ct) {
    const int cur = ct & 1;
    if (ct + 1 < 32) {
      const ushort* panel = ef + (size_t)(ct + 1) * (64 * E_DIM);
      char* dst = sm + (cur ^ 1) * 32768;
#pragma unroll
      for (int i = 0; i < 4; ++i) {
        const int g = i * 512 + tid;
        const int cg = g >> 9, kk = (g >> 6) & 7;
        const int cs = g & 15, ks = (g >> 4) & 3;
        gload_lds16(panel + (size_t)(cg * 16 + cs) * E_DIM + kk * 32 + ks * 8,
                    dst + g * 16);
      }
    }
    float bc[4];
#pragma unroll
    for (int cg = 0; cg < 4; ++cg) bc[cg] = b[ct * 64 + cg * 16 + c16];

    f32x4 acc[4];
#pragma unroll
    for (int cg = 0; cg < 4; ++cg) acc[cg] = (f32x4){0.f, 0.f, 0.f, 0.f};

    const char* lb = sm + cur * 32768;
#pragma unroll
    for (int kk = 0; kk < 8; ++kk) {
      half8 Bf[4];
#pragma unroll
      for (int cg = 0; cg < 4; ++cg)
        Bf[cg] = *(const half8*)(lb + ((((cg << 3) | kk) << 6 | l) << 4));
#pragma unroll
      for (int cg = 0; cg < 4; ++cg)
        acc[cg] = __builtin_amdgcn_mfma_f32_16x16x32_f16(
            Az[kk], Bf[cg], acc[cg], 0, 0, 0);
    }

    // epilogue: s~ = b - acc/1024, running min + candidate collect
    float sv[4][4];
#pragma unroll
    for (int cg = 0; cg < 4; ++cg)
#pragma unroll
      for (int r = 0; r < 4; ++r)
        sv[cg][r] = __fmaf_rn(acc[cg][r], -0.0009765625f, bc[cg]);
    float tmin[4];
#pragma unroll
    for (int r = 0; r < 4; ++r)
      tmin[r] = fminf(fminf(sv[0][r], sv[1][r]), fminf(sv[2][r], sv[3][r]));
#pragma unroll
    for (int m = 1; m < 16; m <<= 1)
#pragma unroll
      for (int r = 0; r < 4; ++r)
        tmin[r] = fminf(tmin[r], __shfl_xor(tmin[r], m, 64));
    float thr[4];
    bool anyc = false;
#pragma unroll
    for (int r = 0; r < 4; ++r) {
      runmin[r] = fminf(runmin[r], tmin[r]);
      thr[r] = runmin[r] + MGN;
    }
#pragma unroll
    for (int cg = 0; cg < 4; ++cg)
#pragma unroll
      for (int r = 0; r < 4; ++r) anyc |= (sv[cg][r] <= thr[r]);
    if (__any(anyc)) {
#pragma unroll
      for (int cg = 0; cg < 4; ++cg)
#pragma unroll
        for (int r = 0; r < 4; ++r)
          if (sv[cg][r] <= thr[r]) {
            const int tokl = wv * 16 + kb * 4 + r;
            const int p = atomicAdd(&s_cnt[tokl], 1);
            if (p < CMAX) {
              s_idx[tokl * CMAX + p] = (ushort)(ct * 64 + cg * 16 + c16);
              s_val[tokl * CMAX + p] = sv[cg][r];
            }
          }
    }
    __syncthreads();
  }

  if (c16 == 0) {
#pragma unroll
    for (int r = 0; r < 4; ++r)
      s_rmin[wv * 16 + kb * 4 + r] = runmin[r];
  }
  __syncthreads();

  if (tid < 128) {
    const int t = blockIdx.x * 128 + tid;
    const int cnt = s_cnt[tid];
    if (cnt > CMAX) {
      gcnt[t] = 1000;  // overflow sentinel -> in-refgather full scan
    } else {
      const float thr = s_rmin[tid] + MGN;
      int nk = 0;
      for (int p = 0; p < cnt; ++p)
        if (s_val[tid * CMAX + p] <= thr)
          gcand[(size_t)t * CMAX + nk++] = s_idx[tid * CMAX + p];
      gcnt[t] = nk;
    }
  }
}

// ---------------------------------------------------------------------------
// k_refgather v3: fallback folded in as rare phase 0.
//   phase 0 (expected empty): block-cooperative exact full scan for any
//     poisoned token among this block's 128 (identical math to the old
//     k_fallback kernel); writes s_bj/idxF/out_idx/counts.
//   phase 1: 2-threads-per-token parity-split exact refine (R21, verified).
//   phase 2: gather z_q + z_q_st write + f64 loss partials (R20, verified).
// Histogram atomics are order-independent => final state identical to R21.
// ---------------------------------------------------------------------------
__global__ __launch_bounds__(256) void k_refgather(
    const float* __restrict__ z, const float* __restrict__ E,
    const float* __restrict__ a, const float* __restrict__ b,
    const int* __restrict__ gcnt, const ushort* __restrict__ gcand,
    int* __restrict__ idxF, float* __restrict__ out_idx,
    int* __restrict__ counts, float* __restrict__ out0,
    double* __restrict__ lossPart) {
  __shared__ int s_bj[128];
  __shared__ double red[256];
  __shared__ int s_pois[128];
  __shared__ int s_np;
  __shared__ float frv[256];
  __shared__ int fri[256];
  const int tid = threadIdx.x;
  const int t0 = blockIdx.x * 128;

  // ---- phase 0: collect & resolve poisoned tokens (expected none) ----
  if (tid == 0) s_np = 0;
  __syncthreads();
  if (tid < 128) {
    if (gcnt[t0 + tid] > CMAX) {
      const int p = atomicAdd(&s_np, 1);
      s_pois[p] = tid;
    }
  }
  __syncthreads();
  const int np = s_np;
  for (int i = 0; i < np; ++i) {
    const int tl = s_pois[i];
    const int t = t0 + tl;
    const float* zp = z + (size_t)t * E_DIM;
    float bv = FLT_MAX;
    int bj = 1 << 30;
    for (int c = tid; c < N_E; c += 256) {
      const float m = chain_m(zp, E + (size_t)c * E_DIM);
      const float D = __fsub_rn(__fadd_rn(a[t], b[c]), __fmul_rn(2.0f, m));
      if (D < bv || (D == bv && c < bj)) { bv = D; bj = c; }
    }
    frv[tid] = bv;
    fri[tid] = bj;
    __syncthreads();
    for (int s = 128; s; s >>= 1) {
      if (tid < s) {
        const float ov = frv[tid + s];
        const int oj = fri[tid + s];
        if (ov < frv[tid] || (ov == frv[tid] && oj < fri[tid])) {
          frv[tid] = ov;
          fri[tid] = oj;
        }
      }
      __syncthreads();
    }
    if (tid == 0) {
      s_bj[tl] = fri[0];
      idxF[t] = fri[0];
      out_idx[t] = (float)fri[0];
      atomicAdd(&counts[fri[0]], 1);
    }
    __syncthreads();
  }

  // ---- phase 1: parity-split exact refine (2 threads per token) ----
  {
    const int tl = tid >> 1;          // token within block, 0..127
    const int sub = tid & 1;          // candidate-parity lane of the pair
    const int t = t0 + tl;
    const int cnt = gcnt[t];
    if (cnt <= CMAX) {
      int bestj;
      if (cnt == 1) {
        bestj = gcand[(size_t)t * CMAX];
      } else {
        float bv = FLT_MAX;
        int bj = 1 << 30;
        const float* zp = z + (size_t)t * E_DIM;
        for (int p = sub; p < cnt; p += 2) {
          const int c = gcand[(size_t)t * CMAX + p];
          const float m = chain_m(zp, E + (size_t)c * E_DIM);
          const float D = __fsub_rn(__fadd_rn(a[t], b[c]), __fmul_rn(2.0f, m));
          if (D < bv || (D == bv && c < bj)) { bv = D; bj = c; }
        }
        const float ov = __shfl_xor(bv, 1, 64);
        const int oj = __shfl_xor(bj, 1, 64);
        if (ov < bv || (ov == bv && oj < bj)) { bv = ov; bj = oj; }
        bestj = bj;
      }
      if (sub == 0) {
        s_bj[tl] = bestj;
        idxF[t] = bestj;
        out_idx[t] = (float)bestj;
        atomicAdd(&counts[bestj], 1);
      }
    }
  }
  __syncthreads();

  // ---- phase 2: gather z_q, z_q_st = fl(z + fl(zq - z)), f64 loss ----
  double ls = 0.0;
#pragma unroll 4
  for (int i = 0; i < 32; ++i) {
    const int u = i * 256 + tid;          // 0..8191 float4 units
    const int tl = u >> 6;
    const int d4 = (u & 63) * 4;
    const int c = s_bj[tl];
    const size_t tok = (size_t)t0 + tl;
    const float4 zq = *(const float4*)&E[(size_t)c * E_DIM + d4];
    const float4 zv = *(const float4*)&z[tok * E_DIM + d4];
    float4 o;
    o.x = __fadd_rn(zv.x, __fsub_rn(zq.x, zv.x));
    o.y = __fadd_rn(zv.y, __fsub_rn(zq.y, zv.y));
    o.z = __fadd_rn(zv.z, __fsub_rn(zq.z, zv.z));
    o.w = __fadd_rn(zv.w, __fsub_rn(zq.w, zv.w));
    *(float4*)&out0[tok * E_DIM + d4] = o;
    double dx;
    dx = (double)zq.x - (double)zv.x; ls += dx * dx;
    dx = (double)zq.y - (double)zv.y; ls += dx * dx;
    dx = (double)zq.z - (double)zv.z; ls += dx * dx;
    dx = (double)zq.w - (double)zv.w; ls += dx * dx;
  }
  red[tid] = ls;
  __syncthreads();
  for (int s = 128; s; s >>= 1) {
    if (tid < s) red[tid] += red[tid + s];
    __syncthreads();
  }
  if (tid == 0) lossPart[blockIdx.x] = red[0];
}

__global__ __launch_bounds__(256) void k_final(
    const double* __restrict__ lossPart, const int* __restrict__ counts,
    float* __restrict__ outLoss, float* __restrict__ outPerp) {
  __shared__ double rs[256], rh[256];
  double s = 0.0, h = 0.0;
  for (int j = threadIdx.x; j < 512; j += 256) s += lossPart[j];
  for (int j = threadIdx.x; j < N_E; j += 256) {
    const double p = (double)counts[j] * (1.0 / (double)N_TOK);
    h -= p * log(p + 1e-10);
  }
  rs[threadIdx.x] = s;
  rh[threadIdx.x] = h;
  __syncthreads();
  for (int m = 128; m; m >>= 1) {
    if (threadIdx.x < m) {
      rs[threadIdx.x] += rs[threadIdx.x + m];
      rh[threadIdx.x] += rh[threadIdx.x + m];
    }
    __syncthreads();
  }
  if (threadIdx.x == 0) {
    outLoss[0] = (float)((1.0 + BETA) * rs[0] / (double)((size_t)N_TOK * E_DIM));
    outPerp[0] = (float)exp(rh[0]);
  }
}

extern "C" void kernel_launch(void* const* d_in, const int* in_sizes, int n_in,
                              void* d_out, int out_size, void* d_ws, size_t ws_size,
                              hipStream_t stream) {
  const float* z = (const float*)d_in[0];
  const float* E = (const float*)d_in[1];

  float* out0 = (float*)d_out;                       // z_q_st [65536*256]
  float* outLoss = out0 + (size_t)N_TOK * E_DIM;
  float* outPerp = outLoss + 1;
  float* outIdx = outPerp + 1;                       // idx as float [65536]

  char* ws = (char*)d_ws;
  double* lossPart = (double*)(ws + WS_LOSSPART);
  float* a = (float*)(ws + WS_A);
  float* b = (float*)(ws + WS_B);
  int* idxF = (int*)(ws + WS_IDXF);
  int* counts = (int*)(ws + WS_COUNTS);
  int* gcnt = (int*)(ws + WS_CCNT);
  ushort* gcand = (ushort*)(ws + WS_CAND);

  // fp16 operands live in the z_q_st output region (34.6 MB < 64 MB);
  // k_refgather fully overwrites that region afterwards. Deterministic.
  ushort* zf = (ushort*)out0;
  ushort* ef = zf + (size_t)N_TOK * E_DIM;

  (void)hipFuncSetAttribute(reinterpret_cast<const void*>(k_mfma),
                            hipFuncAttributeMaxDynamicSharedMemorySize, 78848);

  hipLaunchKernelGGL(k_prep, dim3(2048), dim3(256), 0, stream,
                     z, E, zf, ef, a, b, counts);
  hipLaunchKernelGGL(k_mfma, dim3(N_TOK / 128), dim3(512), 78848, stream,
                     zf, ef, b, gcnt, gcand);
  hipLaunchKernelGGL(k_refgather, dim3(N_TOK / 128), dim3(256), 0, stream,
                     z, E, a, b, gcnt, gcand, idxF, outIdx, counts, out0,
                     lossPart);
  hipLaunchKernelGGL(k_final, dim3(1), dim3(256), 0, stream,
                     lossPart, counts, outLoss, outPerp);
}